// Round 6
// baseline (462.589 us; speedup 1.0000x reference)
//
#include <hip/hip_runtime.h>
#include <hip/hip_bf16.h>

#define NN 16384
#define DD 256

typedef unsigned short u16;
typedef unsigned int u32;
typedef __attribute__((ext_vector_type(8))) __bf16 bf16x8;
typedef __attribute__((ext_vector_type(4))) float f32x4;

// ---------- helpers ----------
static __device__ __forceinline__ u16 f2bf(float f) {
    u32 u = __float_as_uint(f);
    u32 r = (u + 0x7fffu + ((u >> 16) & 1u)) >> 16;   // RNE
    return (u16)r;
}

// async global->LDS, 16B per lane; LDS dest = wave-uniform base + lane*16
static __device__ __forceinline__ void gload16(const u16* g, u16* l) {
    __builtin_amdgcn_global_load_lds(
        (const __attribute__((address_space(1))) void*)g,
        (__attribute__((address_space(3))) void*)l,
        16, 0, 0);
}

// ---------- kernel 1: convert to bf16 (image scaled by log2(e)), zero sums ----------
__global__ void prep_kernel(const float* __restrict__ img, const float* __restrict__ txt,
                            u16* __restrict__ Abf, u16* __restrict__ Bbf,
                            float* __restrict__ zbuf /* s_row..s_col */, float* __restrict__ out) {
    int gid = blockIdx.x * 256 + threadIdx.x;          // 0 .. 1048575  (N*D/4)
    float4 va = ((const float4*)img)[gid];
    float4 vb = ((const float4*)txt)[gid];
    ushort4 ua, ub;
    const float S = 1.44269504088896f;                  // log2(e)
    ua.x = f2bf(va.x * S); ua.y = f2bf(va.y * S); ua.z = f2bf(va.z * S); ua.w = f2bf(va.w * S);
    ub.x = f2bf(vb.x);     ub.y = f2bf(vb.y);     ub.z = f2bf(vb.z);     ub.w = f2bf(vb.w);
    ((ushort4*)Abf)[gid] = ua;
    ((ushort4*)Bbf)[gid] = ub;
    if (gid < 32768) zbuf[gid] = 0.0f;
    if (gid == 0) out[0] = 0.0f;
}

// ---------- kernel 2: fused GEMM + exp2 + row/col sum + diag ----------
// Grid: 1024 blocks = 128 bi x 8 jg (bi-major: resident blocks on a CU share
// the A panel -> L1/L2 hits, and hit disjoint s_col ranges). Block: 128-row
// panel, persistent sweep over 16 column tiles (rotated by bi to spread
// col-atomics and diag work). Per K-chunk, stage A-tile AND B-tile (16+16 KB,
// m97 regime) with the R2 layout that measured ZERO bank conflicts:
// 128 B rows, chunk XOR-swizzle (LDS(row,c) holds global chunk c^(row&7)).
// LDS 32 KB + ~90 VGPR -> 4 blocks/CU resident (16 waves/CU) for drain hiding.
// Epilogue register-only: row partials accumulate across all 16 tiles (one
// butterfly + atomic per block); col sums 2 shuffles + 1 atomic per tile;
// acc zero-init folded into the first MFMA of each tile (C=0).
__global__ __launch_bounds__(256, 4) void gemm_lse_kernel(
        const u16* __restrict__ Abf, const u16* __restrict__ Bbf,
        float* __restrict__ s_row, float* __restrict__ s_col,
        float* __restrict__ diag) {
    __shared__ u16 sA[128 * 64];    // row stride 128 B = 8 chunks of 16 B
    __shared__ u16 sB[128 * 64];

    const int t = threadIdx.x;
    const int lane = t & 63;
    const int w = t >> 6;
    const int wr = w >> 1, wc = w & 1;
    const int q = lane >> 4, m = lane & 15;
    const int bi = blockIdx.x >> 3;
    const int jg = blockIdx.x & 7;
    const int row0 = bi << 7;

    // staging decomposition: wave w covers tile-rows [w*32, w*32+32)
    const int srow = w << 5;
    const int lr = lane >> 3;       // row within 8-row group
    const int cc8 = lane & 7;       // LDS chunk within row
    const int gch = cc8 ^ lr;       // swizzled global chunk (row & 7 == lr)

    const f32x4 fzero = {0.f, 0.f, 0.f, 0.f};
    f32x4 acc[4][4];
    f32x4 rp[4] = {fzero, fzero, fzero, fzero};   // row partials, whole block

    #pragma unroll 1
    for (int jt = 0; jt < 16; ++jt) {
        const int jtt = (jt + bi) & 15;               // rotated tile index
        const int col0 = ((jg << 4) + jtt) << 7;
        #pragma unroll
        for (int kc = 0; kc < 4; ++kc) {
            const int kb = kc << 6;
            __syncthreads();   // prior compute done with sA/sB
            {
                const size_t abase = (size_t)(row0 + srow + lr) * DD + kb + (gch << 3);
                const size_t bbase = (size_t)(col0 + srow + lr) * DD + kb + (gch << 3);
                #pragma unroll
                for (int jj = 0; jj < 4; ++jj) {
                    gload16(Abf + abase + (size_t)(jj << 3) * DD,
                            &sA[(srow + (jj << 3)) << 6]);
                    gload16(Bbf + bbase + (size_t)(jj << 3) * DD,
                            &sB[(srow + (jj << 3)) << 6]);
                }
            }
            __syncthreads();   // drains vmcnt -> sA/sB chunk ready
            #pragma unroll
            for (int s = 0; s < 2; ++s) {
                const int k8 = (s << 2) + q;           // chunk in row, 0..7
                bf16x8 af[4], bfv[4];
                #pragma unroll
                for (int rb = 0; rb < 4; ++rb) {
                    const int rr = (wr << 6) + (rb << 4) + m;
                    af[rb]  = *(const bf16x8*)(&sA[(rr << 6) + ((k8 ^ (m & 7)) << 3)]);
                    const int ccr = (wc << 6) + (rb << 4) + m;
                    bfv[rb] = *(const bf16x8*)(&sB[(ccr << 6) + ((k8 ^ (m & 7)) << 3)]);
                }
                if (kc == 0 && s == 0) {
                    #pragma unroll
                    for (int rb = 0; rb < 4; ++rb)
                        #pragma unroll
                        for (int cb = 0; cb < 4; ++cb)
                            acc[rb][cb] = __builtin_amdgcn_mfma_f32_16x16x32_bf16(
                                af[rb], bfv[cb], fzero, 0, 0, 0);
                } else {
                    #pragma unroll
                    for (int rb = 0; rb < 4; ++rb)
                        #pragma unroll
                        for (int cb = 0; cb < 4; ++cb)
                            acc[rb][cb] = __builtin_amdgcn_mfma_f32_16x16x32_bf16(
                                af[rb], bfv[cb], acc[rb][cb], 0, 0, 0);
                }
            }
        }

        // ---- per-tile epilogue (registers + global atomics only) ----
        // diag (pre-exp, log2-scaled): D layout col=m, row=q*4+r
        if (bi == ((jg << 4) + jtt) && wr == wc) {
            #pragma unroll
            for (int rb = 0; rb < 4; ++rb)
                #pragma unroll
                for (int r = 0; r < 4; ++r)
                    if (m == ((q << 2) | r))
                        diag[row0 + (wr << 6) + (rb << 4) + m] = acc[rb][rb][r];
        }
        // exp2(l' - 144) in place
        #pragma unroll
        for (int rb = 0; rb < 4; ++rb)
            #pragma unroll
            for (int cb = 0; cb < 4; ++cb)
                #pragma unroll
                for (int r = 0; r < 4; ++r)
                    acc[rb][cb][r] = __builtin_amdgcn_exp2f(acc[rb][cb][r] - 144.0f);

        // row partials: pure VALU, reduced once at block end
        #pragma unroll
        for (int rb = 0; rb < 4; ++rb)
            rp[rb] += (acc[rb][0] + acc[rb][1]) + (acc[rb][2] + acc[rb][3]);

        // col partials: in-lane adds + 2 cross-quad shuffles; lane keeps cb==q
        float cpart = 0.0f;
        #pragma unroll
        for (int cb = 0; cb < 4; ++cb) {
            float v = 0.0f;
            #pragma unroll
            for (int rb = 0; rb < 4; ++rb)
                v += (acc[rb][cb][0] + acc[rb][cb][1]) + (acc[rb][cb][2] + acc[rb][cb][3]);
            v += __shfl_xor(v, 16, 64);
            v += __shfl_xor(v, 32, 64);
            if (q == cb) cpart = v;
        }
        atomicAdd(&s_col[col0 + (wc << 6) + (q << 4) + m], cpart);
    }

    // ---- block-end row reduction: rp[rb][r] is row (wr*64+rb*16+q*4+r),
    // distributed over the 16 m-lanes of quad q. Butterfly over m.
    float rout = 0.0f;
    #pragma unroll
    for (int rb = 0; rb < 4; ++rb)
        #pragma unroll
        for (int r = 0; r < 4; ++r) {
            float v = rp[rb][r];
            v += __shfl_xor(v, 1, 16);
            v += __shfl_xor(v, 2, 16);
            v += __shfl_xor(v, 4, 16);
            v += __shfl_xor(v, 8, 16);
            if (m == ((rb << 2) | r)) rout = v;
        }
    atomicAdd(&s_row[row0 + (wr << 6) + ((m >> 2) << 4) + (q << 2) + (m & 3)], rout);
}

// ---------- kernel 3: final reduce (64 blocks, 256 rows each) ----------
__global__ void final_kernel(const float* __restrict__ s_row, const float* __restrict__ s_col,
                             const float* __restrict__ diag, float* __restrict__ out) {
    __shared__ double red[256];
    int t = threadIdx.x;
    int i = blockIdx.x * 256 + t;
    double p = 0.5 * (double)(log2f(s_row[i]) + log2f(s_col[i])) + 144.0 - (double)diag[i];
    red[t] = p;
    __syncthreads();
    for (int s = 128; s > 0; s >>= 1) {
        if (t < s) red[t] += red[t + s];
        __syncthreads();
    }
    if (t == 0) atomicAdd(out, (float)(red[0] * 0.6931471805599453 / (double)NN));
}

// ---------- launch ----------
extern "C" void kernel_launch(void* const* d_in, const int* in_sizes, int n_in,
                              void* d_out, int out_size, void* d_ws, size_t ws_size,
                              hipStream_t stream) {
    const float* img = (const float*)d_in[0];
    const float* txt = (const float*)d_in[1];
    char* ws = (char*)d_ws;
    u16*   Abf   = (u16*)ws;                               // 8 MB
    u16*   Bbf   = (u16*)(ws + 8388608);                   // 8 MB
    float* s_row = (float*)(ws + 16777216);                // 64 KB
    float* s_col = (float*)(ws + 16777216 + 65536);        // 64 KB
    float* diag  = (float*)(ws + 16777216 + 131072);       // 64 KB
    float* out   = (float*)d_out;

    prep_kernel<<<4096, 256, 0, stream>>>(img, txt, Abf, Bbf, s_row, out);
    gemm_lse_kernel<<<1024, 256, 0, stream>>>(Abf, Bbf, s_row, s_col, diag);
    final_kernel<<<64, 256, 0, stream>>>(s_row, s_col, diag, out);
}

// Round 7
// 355.141 us; speedup vs baseline: 1.3025x; 1.3025x over previous
//
#include <hip/hip_runtime.h>
#include <hip/hip_bf16.h>

#define NN 16384
#define DD 256

typedef unsigned short u16;
typedef unsigned int u32;
typedef __attribute__((ext_vector_type(8))) __bf16 bf16x8;
typedef __attribute__((ext_vector_type(4))) float f32x4;

// ---------- helpers ----------
static __device__ __forceinline__ u16 f2bf(float f) {
    u32 u = __float_as_uint(f);
    u32 r = (u + 0x7fffu + ((u >> 16) & 1u)) >> 16;   // RNE
    return (u16)r;
}

// async global->LDS, 16B per lane; LDS dest = wave-uniform base + lane*16
static __device__ __forceinline__ void gload16(const u16* g, u16* l) {
    __builtin_amdgcn_global_load_lds(
        (const __attribute__((address_space(1))) void*)g,
        (__attribute__((address_space(3))) void*)l,
        16, 0, 0);
}

// ---------- kernel 1: convert to bf16 (image scaled by log2(e)), zero sums ----------
__global__ void prep_kernel(const float* __restrict__ img, const float* __restrict__ txt,
                            u16* __restrict__ Abf, u16* __restrict__ Bbf,
                            float* __restrict__ zbuf /* s_row..s_col */, float* __restrict__ out) {
    int gid = blockIdx.x * 256 + threadIdx.x;          // 0 .. 1048575  (N*D/4)
    float4 va = ((const float4*)img)[gid];
    float4 vb = ((const float4*)txt)[gid];
    ushort4 ua, ub;
    const float S = 1.44269504088896f;                  // log2(e)
    ua.x = f2bf(va.x * S); ua.y = f2bf(va.y * S); ua.z = f2bf(va.z * S); ua.w = f2bf(va.w * S);
    ub.x = f2bf(vb.x);     ub.y = f2bf(vb.y);     ub.z = f2bf(vb.z);     ub.w = f2bf(vb.w);
    ((ushort4*)Abf)[gid] = ua;
    ((ushort4*)Bbf)[gid] = ub;
    if (gid < 32768) zbuf[gid] = 0.0f;
    if (gid == 0) out[0] = 0.0f;
}

// ---------- kernel 2: fused GEMM + exp2 + row/col sum + diag ----------
// Grid: 1024 blocks = 8 jg x 128 bi, bi FAST (blockIdx = jg*128 + bi): the
// ~concurrently-resident blocks of a jg group sweep the SAME column tile in
// phase -> B re-reads are L2-hot (R2/R5 measured ~40 MB FETCH), and their A
// panels form a contiguous L2-resident slice. NO tile rotation (R6's rotation
// caused 1.07 GB of HBM fetch). Per K-chunk, stage A-tile AND B-tile
// (16+16 KB) in the layout that measured ZERO conflicts: 128 B rows, chunk
// XOR-swizzle (LDS(row,c) = global chunk c^(row&7)). 32 KB LDS + 64 VGPR ->
// 4 blocks/CU (16 waves/CU) for barrier-drain hiding (R6 measured 44% occ).
// Epilogue register-only: row partials accumulate across all 16 tiles (one
// butterfly + atomic per block); col sums 2 shuffles + 1 atomic per tile;
// acc zero-init folded into the first MFMA of each tile (C=0).
__global__ __launch_bounds__(256, 4) void gemm_lse_kernel(
        const u16* __restrict__ Abf, const u16* __restrict__ Bbf,
        float* __restrict__ s_row, float* __restrict__ s_col,
        float* __restrict__ diag) {
    __shared__ u16 sA[128 * 64];    // row stride 128 B = 8 chunks of 16 B
    __shared__ u16 sB[128 * 64];

    const int t = threadIdx.x;
    const int lane = t & 63;
    const int w = t >> 6;
    const int wr = w >> 1, wc = w & 1;
    const int q = lane >> 4, m = lane & 15;
    const int bi = blockIdx.x & 127;            // FAST: resident blocks share B phase
    const int jg = blockIdx.x >> 7;
    const int row0 = bi << 7;

    // staging decomposition: wave w covers tile-rows [w*32, w*32+32)
    const int srow = w << 5;
    const int lr = lane >> 3;       // row within 8-row group
    const int cc8 = lane & 7;       // LDS chunk within row
    const int gch = cc8 ^ lr;       // swizzled global chunk (row & 7 == lr)

    const f32x4 fzero = {0.f, 0.f, 0.f, 0.f};
    f32x4 acc[4][4];
    f32x4 rp[4] = {fzero, fzero, fzero, fzero};   // row partials, whole block

    #pragma unroll 1
    for (int jt = 0; jt < 16; ++jt) {
        const int col0 = ((jg << 4) + jt) << 7;
        #pragma unroll
        for (int kc = 0; kc < 4; ++kc) {
            const int kb = kc << 6;
            __syncthreads();   // prior compute done with sA/sB
            {
                const size_t abase = (size_t)(row0 + srow + lr) * DD + kb + (gch << 3);
                const size_t bbase = (size_t)(col0 + srow + lr) * DD + kb + (gch << 3);
                #pragma unroll
                for (int jj = 0; jj < 4; ++jj) {
                    gload16(Abf + abase + (size_t)(jj << 3) * DD,
                            &sA[(srow + (jj << 3)) << 6]);
                    gload16(Bbf + bbase + (size_t)(jj << 3) * DD,
                            &sB[(srow + (jj << 3)) << 6]);
                }
            }
            __syncthreads();   // drains vmcnt -> sA/sB chunk ready
            #pragma unroll
            for (int s = 0; s < 2; ++s) {
                const int k8 = (s << 2) + q;           // chunk in row, 0..7
                bf16x8 af[4], bfv[4];
                #pragma unroll
                for (int rb = 0; rb < 4; ++rb) {
                    const int rr = (wr << 6) + (rb << 4) + m;
                    af[rb]  = *(const bf16x8*)(&sA[(rr << 6) + ((k8 ^ (m & 7)) << 3)]);
                    const int ccr = (wc << 6) + (rb << 4) + m;
                    bfv[rb] = *(const bf16x8*)(&sB[(ccr << 6) + ((k8 ^ (m & 7)) << 3)]);
                }
                if (kc == 0 && s == 0) {
                    #pragma unroll
                    for (int rb = 0; rb < 4; ++rb)
                        #pragma unroll
                        for (int cb = 0; cb < 4; ++cb)
                            acc[rb][cb] = __builtin_amdgcn_mfma_f32_16x16x32_bf16(
                                af[rb], bfv[cb], fzero, 0, 0, 0);
                } else {
                    #pragma unroll
                    for (int rb = 0; rb < 4; ++rb)
                        #pragma unroll
                        for (int cb = 0; cb < 4; ++cb)
                            acc[rb][cb] = __builtin_amdgcn_mfma_f32_16x16x32_bf16(
                                af[rb], bfv[cb], acc[rb][cb], 0, 0, 0);
                }
            }
        }

        // ---- per-tile epilogue (registers + global atomics only) ----
        // diag (pre-exp, log2-scaled): D layout col=m, row=q*4+r
        if (bi == ((jg << 4) + jt) && wr == wc) {
            #pragma unroll
            for (int rb = 0; rb < 4; ++rb)
                #pragma unroll
                for (int r = 0; r < 4; ++r)
                    if (m == ((q << 2) | r))
                        diag[row0 + (wr << 6) + (rb << 4) + m] = acc[rb][rb][r];
        }
        // exp2(l' - 144) in place
        #pragma unroll
        for (int rb = 0; rb < 4; ++rb)
            #pragma unroll
            for (int cb = 0; cb < 4; ++cb)
                #pragma unroll
                for (int r = 0; r < 4; ++r)
                    acc[rb][cb][r] = __builtin_amdgcn_exp2f(acc[rb][cb][r] - 144.0f);

        // row partials: pure VALU, reduced once at block end
        #pragma unroll
        for (int rb = 0; rb < 4; ++rb)
            rp[rb] += (acc[rb][0] + acc[rb][1]) + (acc[rb][2] + acc[rb][3]);

        // col partials: in-lane adds + 2 cross-quad shuffles; lane keeps cb==q
        float cpart = 0.0f;
        #pragma unroll
        for (int cb = 0; cb < 4; ++cb) {
            float v = 0.0f;
            #pragma unroll
            for (int rb = 0; rb < 4; ++rb)
                v += (acc[rb][cb][0] + acc[rb][cb][1]) + (acc[rb][cb][2] + acc[rb][cb][3]);
            v += __shfl_xor(v, 16, 64);
            v += __shfl_xor(v, 32, 64);
            if (q == cb) cpart = v;
        }
        atomicAdd(&s_col[col0 + (wc << 6) + (q << 4) + m], cpart);
    }

    // ---- block-end row reduction: rp[rb][r] is row (wr*64+rb*16+q*4+r),
    // distributed over the 16 m-lanes of quad q. Butterfly over m.
    float rout = 0.0f;
    #pragma unroll
    for (int rb = 0; rb < 4; ++rb)
        #pragma unroll
        for (int r = 0; r < 4; ++r) {
            float v = rp[rb][r];
            v += __shfl_xor(v, 1, 16);
            v += __shfl_xor(v, 2, 16);
            v += __shfl_xor(v, 4, 16);
            v += __shfl_xor(v, 8, 16);
            if (m == ((rb << 2) | r)) rout = v;
        }
    atomicAdd(&s_row[row0 + (wr << 6) + ((m >> 2) << 4) + (q << 2) + (m & 3)], rout);
}

// ---------- kernel 3: final reduce (64 blocks, 256 rows each) ----------
__global__ void final_kernel(const float* __restrict__ s_row, const float* __restrict__ s_col,
                             const float* __restrict__ diag, float* __restrict__ out) {
    __shared__ double red[256];
    int t = threadIdx.x;
    int i = blockIdx.x * 256 + t;
    double p = 0.5 * (double)(log2f(s_row[i]) + log2f(s_col[i])) + 144.0 - (double)diag[i];
    red[t] = p;
    __syncthreads();
    for (int s = 128; s > 0; s >>= 1) {
        if (t < s) red[t] += red[t + s];
        __syncthreads();
    }
    if (t == 0) atomicAdd(out, (float)(red[0] * 0.6931471805599453 / (double)NN));
}

// ---------- launch ----------
extern "C" void kernel_launch(void* const* d_in, const int* in_sizes, int n_in,
                              void* d_out, int out_size, void* d_ws, size_t ws_size,
                              hipStream_t stream) {
    const float* img = (const float*)d_in[0];
    const float* txt = (const float*)d_in[1];
    char* ws = (char*)d_ws;
    u16*   Abf   = (u16*)ws;                               // 8 MB
    u16*   Bbf   = (u16*)(ws + 8388608);                   // 8 MB
    float* s_row = (float*)(ws + 16777216);                // 64 KB
    float* s_col = (float*)(ws + 16777216 + 65536);        // 64 KB
    float* diag  = (float*)(ws + 16777216 + 131072);       // 64 KB
    float* out   = (float*)d_out;

    prep_kernel<<<4096, 256, 0, stream>>>(img, txt, Abf, Bbf, s_row, out);
    gemm_lse_kernel<<<1024, 256, 0, stream>>>(Abf, Bbf, s_row, s_col, diag);
    final_kernel<<<64, 256, 0, stream>>>(s_row, s_col, diag, out);
}

// Round 8
// 202.277 us; speedup vs baseline: 2.2869x; 1.7557x over previous
//
#include <hip/hip_runtime.h>
#include <hip/hip_bf16.h>

#define NN 16384
#define DD 256

typedef unsigned short u16;
typedef unsigned int u32;
typedef unsigned char u8;
typedef long i64;
typedef __attribute__((ext_vector_type(4))) float f32x4;

// async global->LDS, 16B per lane; LDS dest = wave-uniform base + lane*16
static __device__ __forceinline__ void gload16(const u8* g, u8* l) {
    __builtin_amdgcn_global_load_lds(
        (const __attribute__((address_space(1))) void*)g,
        (__attribute__((address_space(3))) void*)l,
        16, 0, 0);
}

// ---------- kernel 1: convert to fp8 e4m3 (image scaled by log2(e)), zero sums ----------
__global__ void prep_kernel(const float* __restrict__ img, const float* __restrict__ txt,
                            u8* __restrict__ A8, u8* __restrict__ B8,
                            float* __restrict__ zbuf /* s_row..s_col */, float* __restrict__ out) {
    int gid = blockIdx.x * 256 + threadIdx.x;          // 0 .. 1048575  (N*D/4)
    float4 va = ((const float4*)img)[gid];
    float4 vb = ((const float4*)txt)[gid];
    const float S = 1.44269504088896f;                  // log2(e) folded into A
    int pa = __builtin_amdgcn_cvt_pk_fp8_f32(va.x * S, va.y * S, 0, false);
    pa     = __builtin_amdgcn_cvt_pk_fp8_f32(va.z * S, va.w * S, pa, true);
    int pb = __builtin_amdgcn_cvt_pk_fp8_f32(vb.x, vb.y, 0, false);
    pb     = __builtin_amdgcn_cvt_pk_fp8_f32(vb.z, vb.w, pb, true);
    ((int*)A8)[gid] = pa;
    ((int*)B8)[gid] = pb;
    if (gid < 32768) zbuf[gid] = 0.0f;
    if (gid == 0) out[0] = 0.0f;
}

// ---------- kernel 2: fused fp8 GEMM + exp2 + row/col sum + diag ----------
// R5 structure (measured best memory behavior: FETCH 41 MB, WRITE 17 MB) in fp8:
// Grid 1024 = 8 jg x 128 bi, bi FAST. Block: 128-row panel; A (128x256 fp8 =
// 32 KB) staged into LDS ONCE as 4 kc-chunk buffers; persistent sweep over 16
// column tiles; per K-chunk only B (8 KB) staged. A-once keeps the L2 working
// set ~1 MB/XCD even when persistent blocks drift (R6/R7's per-chunk A
// restaging thrashed L2 -> 551 MB FETCH / 324 MB WRITE).
// LDS 40 KB -> 4 blocks/CU (16 waves/CU), double R5's drain-hiding.
// Layout: 64 B rows, 16 B chunks, swizzle c ^ ((r^(r>>2))&3): enumerated bank
// walk gives 2 lanes/bank per quad (2-way = free, m136).
// fp8 within-lane k-permutation cancels between A and B frags (dot-product
// invariance); diag is computed from the same quantized GEMM (self-consistent).
__global__ __launch_bounds__(256, 4) void gemm_lse_kernel(
        const u8* __restrict__ A8, const u8* __restrict__ B8,
        float* __restrict__ s_row, float* __restrict__ s_col,
        float* __restrict__ diag) {
    __shared__ u8 sA[4][8192];      // 4 kc-chunks: 128 rows x 64 B
    __shared__ u8 sB[8192];

    const int t = threadIdx.x;
    const int lane = t & 63;
    const int w = t >> 6;
    const int wr = w >> 1, wc = w & 1;
    const int q = lane >> 4, m = lane & 15;
    const int bi = blockIdx.x & 127;            // FAST: resident blocks share B phase
    const int jg = blockIdx.x >> 7;
    const int row0 = bi << 7;

    // staging lane decomposition: 256 lanes x 16 B = 4 KB = 64 rows per round
    const int lrow = lane >> 2;     // row within 16-row wave group
    const int lch  = lane & 3;      // LDS chunk position within row

    // ---- stage A panel ONCE: 4 chunk-buffers x 2 rounds
    #pragma unroll
    for (int kc = 0; kc < 4; ++kc)
        #pragma unroll
        for (int R = 0; R < 2; ++R) {
            const int rb0 = (R << 6) + (w << 4);       // wave's row base in buffer
            const int r = rb0 + lrow;
            const int gch = lch ^ ((r ^ (r >> 2)) & 3);
            gload16(A8 + (size_t)(row0 + r) * DD + (kc << 6) + (gch << 4),
                    &sA[kc][rb0 << 6]);
        }

    const f32x4 fzero = {0.f, 0.f, 0.f, 0.f};
    f32x4 acc[4][4];
    f32x4 rp[4] = {fzero, fzero, fzero, fzero};   // row partials, whole block

    #pragma unroll 1
    for (int jt = 0; jt < 16; ++jt) {
        const int col0 = ((jg << 4) + jt) << 7;
        #pragma unroll
        for (int kc = 0; kc < 4; ++kc) {
            __syncthreads();   // prior compute done with sB (A also drained, 1st iter)
            #pragma unroll
            for (int R = 0; R < 2; ++R) {
                const int rb0 = (R << 6) + (w << 4);
                const int r = rb0 + lrow;
                const int gch = lch ^ ((r ^ (r >> 2)) & 3);
                gload16(B8 + (size_t)(col0 + r) * DD + (kc << 6) + (gch << 4),
                        &sB[rb0 << 6]);
            }
            __syncthreads();   // drains vmcnt -> sB chunk ready
            #pragma unroll
            for (int s = 0; s < 2; ++s) {
                // lane covers k bytes kc*64 + s*32 + q*8 .. +8
                const int cs = (s << 1) | (q >> 1);    // 16B chunk of (s,q)
                const int bo = (q & 1) << 3;           // byte offset in chunk
                i64 af[4], bfv[4];
                #pragma unroll
                for (int rb = 0; rb < 4; ++rb) {
                    const int rr = (wr << 6) + (rb << 4) + m;
                    af[rb]  = *(const i64*)(&sA[kc][(rr << 6) +
                                ((cs ^ ((rr ^ (rr >> 2)) & 3)) << 4) + bo]);
                    const int cr = (wc << 6) + (rb << 4) + m;
                    bfv[rb] = *(const i64*)(&sB[(cr << 6) +
                                ((cs ^ ((cr ^ (cr >> 2)) & 3)) << 4) + bo]);
                }
                if (kc == 0 && s == 0) {
                    #pragma unroll
                    for (int rb = 0; rb < 4; ++rb)
                        #pragma unroll
                        for (int cb = 0; cb < 4; ++cb)
                            acc[rb][cb] = __builtin_amdgcn_mfma_f32_16x16x32_fp8_fp8(
                                af[rb], bfv[cb], fzero, 0, 0, 0);
                } else {
                    #pragma unroll
                    for (int rb = 0; rb < 4; ++rb)
                        #pragma unroll
                        for (int cb = 0; cb < 4; ++cb)
                            acc[rb][cb] = __builtin_amdgcn_mfma_f32_16x16x32_fp8_fp8(
                                af[rb], bfv[cb], acc[rb][cb], 0, 0, 0);
                }
            }
        }

        // ---- per-tile epilogue (registers + global atomics only) ----
        // diag (pre-exp, log2-scaled): D layout col=m, row=q*4+r
        if (bi == ((jg << 4) + jt) && wr == wc) {
            #pragma unroll
            for (int rb = 0; rb < 4; ++rb)
                #pragma unroll
                for (int r = 0; r < 4; ++r)
                    if (m == ((q << 2) | r))
                        diag[row0 + (wr << 6) + (rb << 4) + m] = acc[rb][rb][r];
        }
        // exp2(l' - 144) in place
        #pragma unroll
        for (int rb = 0; rb < 4; ++rb)
            #pragma unroll
            for (int cb = 0; cb < 4; ++cb)
                #pragma unroll
                for (int r = 0; r < 4; ++r)
                    acc[rb][cb][r] = __builtin_amdgcn_exp2f(acc[rb][cb][r] - 144.0f);

        // row partials: pure VALU, reduced once at block end
        #pragma unroll
        for (int rb = 0; rb < 4; ++rb)
            rp[rb] += (acc[rb][0] + acc[rb][1]) + (acc[rb][2] + acc[rb][3]);

        // col partials: in-lane adds + 2 cross-quad shuffles; lane keeps cb==q
        float cpart = 0.0f;
        #pragma unroll
        for (int cb = 0; cb < 4; ++cb) {
            float v = 0.0f;
            #pragma unroll
            for (int rb = 0; rb < 4; ++rb)
                v += (acc[rb][cb][0] + acc[rb][cb][1]) + (acc[rb][cb][2] + acc[rb][cb][3]);
            v += __shfl_xor(v, 16, 64);
            v += __shfl_xor(v, 32, 64);
            if (q == cb) cpart = v;
        }
        atomicAdd(&s_col[col0 + (wc << 6) + (q << 4) + m], cpart);
    }

    // ---- block-end row reduction: rp[rb][r] is row (wr*64+rb*16+q*4+r),
    // distributed over the 16 m-lanes of quad q. Butterfly over m.
    float rout = 0.0f;
    #pragma unroll
    for (int rb = 0; rb < 4; ++rb)
        #pragma unroll
        for (int r = 0; r < 4; ++r) {
            float v = rp[rb][r];
            v += __shfl_xor(v, 1, 16);
            v += __shfl_xor(v, 2, 16);
            v += __shfl_xor(v, 4, 16);
            v += __shfl_xor(v, 8, 16);
            if (m == ((rb << 2) | r)) rout = v;
        }
    atomicAdd(&s_row[row0 + (wr << 6) + ((m >> 2) << 4) + (q << 2) + (m & 3)], rout);
}

// ---------- kernel 3: final reduce (64 blocks, 256 rows each) ----------
__global__ void final_kernel(const float* __restrict__ s_row, const float* __restrict__ s_col,
                             const float* __restrict__ diag, float* __restrict__ out) {
    __shared__ double red[256];
    int t = threadIdx.x;
    int i = blockIdx.x * 256 + t;
    double p = 0.5 * (double)(log2f(s_row[i]) + log2f(s_col[i])) + 144.0 - (double)diag[i];
    red[t] = p;
    __syncthreads();
    for (int s = 128; s > 0; s >>= 1) {
        if (t < s) red[t] += red[t + s];
        __syncthreads();
    }
    if (t == 0) atomicAdd(out, (float)(red[0] * 0.6931471805599453 / (double)NN));
}

// ---------- launch ----------
extern "C" void kernel_launch(void* const* d_in, const int* in_sizes, int n_in,
                              void* d_out, int out_size, void* d_ws, size_t ws_size,
                              hipStream_t stream) {
    const float* img = (const float*)d_in[0];
    const float* txt = (const float*)d_in[1];
    char* ws = (char*)d_ws;
    u8*    A8    = (u8*)ws;                                // 4 MB
    u8*    B8    = (u8*)(ws + 4194304);                    // 4 MB
    float* s_row = (float*)(ws + 8388608);                 // 64 KB
    float* s_col = (float*)(ws + 8388608 + 65536);         // 64 KB
    float* diag  = (float*)(ws + 8388608 + 131072);        // 64 KB
    float* out   = (float*)d_out;

    prep_kernel<<<4096, 256, 0, stream>>>(img, txt, A8, B8, s_row, out);
    gemm_lse_kernel<<<1024, 256, 0, stream>>>(A8, B8, s_row, s_col, diag);
    final_kernel<<<64, 256, 0, stream>>>(s_row, s_col, diag, out);
}